// Round 7
// baseline (400.775 us; speedup 1.0000x reference)
//
#include <hip/hip_runtime.h>
#include <math.h>

#define NB    64
#define NS    4096
#define NHQ   32
#define NHKV  8
#define ND    128
#define NG    4            // NHQ / NHKV
#define WAVES 8
#define NTHREADS (WAVES*64)
#define ROUNDS ((NS/WAVES)/4)   // 128 rounds of 4 keys per wave

// exact fp32 -> e4m3fn (RNE, clip +-448) returned as fp32
__device__ __forceinline__ float quant_e4m3(float x) {
    float a = fabsf(x);
    a = fminf(a, 448.0f);
    unsigned ui = __float_as_uint(a);
    int e  = (int)(ui >> 23) - 127;
    int se = (e < -6 ? -6 : e) - 3;          // step exponent (denormal step = 2^-9)
    float stp = __uint_as_float((unsigned)(se + 127) << 23);
    float qv  = rintf(a / stp) * stp;        // a/stp exact (stp is pow2), rintf = RNE
    return copysignf(qv, x);
}

// launch_bounds(512,2): 128-VGPR budget. (512,4) forced 64 VGPRs -> 0.8 GB of
// scratch spill per dispatch (r4/r5 counters: WRITE_SIZE ~836 MB vs 1 MB output).
__global__ __launch_bounds__(NTHREADS, 2) void attn_decode_quant(
    const float* __restrict__ qin,
    const float* __restrict__ kc,
    const float* __restrict__ vc,
    const float* __restrict__ qscale,
    float* __restrict__ out)
{
    __shared__ double s_acc[WAVES][NG][ND];   // 32 KB
    __shared__ double s_l[WAVES][NG];
    __shared__ float  s_m[WAVES][NG];
    __shared__ double s_w[WAVES][NG];
    __shared__ double s_lt[NG];

    // XCD-grouping swizzle: hardware assigns XCD = blockIdx % 8. With
    // b = blockIdx & 63, h = blockIdx >> 6, all 8 h-blocks of batch b get
    // XCD = b % 8 (same XCD) and are co-resident (64 blocks/XCD at 2/CU),
    // so their 512B-column streams of the same 4KB K/V rows merge into
    // contiguous DRAM row reads. Bijective on [0,512).
    const int b    = blockIdx.x & 63;
    const int h    = blockIdx.x >> 6;
    const int tid  = threadIdx.x;
    const int wave = tid >> 6;
    const int lane = tid & 63;
    const int c    = lane >> 4;           // key-slot within round (0..3)
    const int e    = lane & 15;           // elem slot within cluster
    const int half = lane >> 5;
    const int l32  = lane & 31;

    const float sm_scale = (float)(1.0 / (double)sqrtf(128.0f));

    // q fragments, cluster layout: q[b, h*4+g, 4e + 64j .. +4)
    float4 qf[NG][2];
    {
        const float* qb = qin + ((size_t)b * NHQ + (size_t)h * NG) * ND;
        #pragma unroll
        for (int g = 0; g < NG; ++g) {
            #pragma unroll
            for (int j = 0; j < 2; ++j)
                qf[g][j] = *(const float4*)(qb + g * ND + 4 * e + 64 * j);
        }
    }

    const size_t rs = (size_t)NHKV * ND;  // 1024 floats = 4 KB between rows
    const float* kb = kc + ((size_t)b * NS * NHKV + h) * ND;
    const float* vb = vc + ((size_t)b * NS * NHKV + h) * ND;

    const int wbase = wave * (NS / WAVES);        // 512 keys per wave

    const float* kp = kb + (size_t)(wbase + c) * rs + 4 * e;       // rows 4r+c
    const float* vp = vb + (size_t)(wbase + half) * rs + 4 * l32;  // rows 4r+half, +2

    float  m[NG];
    double l[NG];
    double acc[NG][4];
    #pragma unroll
    for (int g = 0; g < NG; ++g) {
        m[g] = -INFINITY; l[g] = 0.0;
        #pragma unroll
        for (int j = 0; j < 4; ++j) acc[g][j] = 0.0;
    }

    // 1-round-deep register pipeline for BOTH K and V
    float4 kqA = *(const float4*)(kp);
    float4 kqB = *(const float4*)(kp + 64);
    float4 vqA = *(const float4*)(vp);
    float4 vqB = *(const float4*)(vp + 2 * rs);

    for (int r = 0; r < ROUNDS; ++r) {
        float4 kfA = kqA, kfB = kqB, vfA = vqA, vfB = vqB;
        int rn = (r + 1 < ROUNDS) ? (r + 1) : r;
        {
            const float* kn = kp + (size_t)(4 * rn) * rs;
            const float* vn = vp + (size_t)(4 * rn) * rs;
            kqA = *(const float4*)(kn);
            kqB = *(const float4*)(kn + 64);
            vqA = *(const float4*)(vn);
            vqB = *(const float4*)(vn + 2 * rs);
        }

        // ---- scores: 4 keys (one per cluster), 16-lane reduce ----
        float s[NG];
        #pragma unroll
        for (int g = 0; g < NG; ++g) {
            float sd = qf[g][0].x * kfA.x;
            sd = fmaf(qf[g][0].y, kfA.y, sd);
            sd = fmaf(qf[g][0].z, kfA.z, sd);
            sd = fmaf(qf[g][0].w, kfA.w, sd);
            sd = fmaf(qf[g][1].x, kfB.x, sd);
            sd = fmaf(qf[g][1].y, kfB.y, sd);
            sd = fmaf(qf[g][1].z, kfB.z, sd);
            sd = fmaf(qf[g][1].w, kfB.w, sd);
            s[g] = sd;
        }
        #pragma unroll
        for (int g = 0; g < NG; ++g) {
            #pragma unroll
            for (int mask = 1; mask < 16; mask <<= 1)
                s[g] += __shfl_xor(s[g], mask);
            s[g] *= sm_scale;
        }

        // wave-uniform round max per group; rare rescale branch (once per 4 keys)
        float rm[NG];
        #pragma unroll
        for (int g = 0; g < NG; ++g) {
            float t = s[g];
            t = fmaxf(t, __shfl_xor(t, 16));
            t = fmaxf(t, __shfl_xor(t, 32));
            rm[g] = t;
        }
        if (rm[0] > m[0] || rm[1] > m[1] || rm[2] > m[2] || rm[3] > m[3]) {
            #pragma unroll
            for (int g = 0; g < NG; ++g) {
                if (rm[g] > m[g]) {
                    double corr = exp((double)(m[g] - rm[g]));   // exp(-inf)=0 first time
                    l[g] *= corr;
                    acc[g][0] *= corr; acc[g][1] *= corr;
                    acc[g][2] *= corr; acc[g][3] *= corr;
                    m[g] = rm[g];
                }
            }
        }

        // p for this lane's key; l accumulates per-cluster (merged at end)
        float p[NG];
        #pragma unroll
        for (int g = 0; g < NG; ++g) {
            p[g] = expf(s[g] - m[g]);
            l[g] += (double)p[g];
        }

        // redistribute p to PV layout via intra-wave shuffles:
        // key A = 4r+half  -> cluster (half)   -> lane half*16
        // key B = 4r+2+half-> cluster (2+half) -> lane half*16+32
        const int srcA = half << 4;
        const int srcB = srcA + 32;
        float pA[NG], pB[NG];
        #pragma unroll
        for (int g = 0; g < NG; ++g) {
            pA[g] = __shfl(p[g], srcA);
            pB[g] = __shfl(p[g], srcB);
        }

        // ---- PV accumulate (fp64), round-1 layout ----
        {
            double vx = (double)vfA.x, vy = (double)vfA.y;
            double vz = (double)vfA.z, vw = (double)vfA.w;
            double p0 = (double)pA[0], p1 = (double)pA[1];
            double p2 = (double)pA[2], p3 = (double)pA[3];
            acc[0][0] = fma(p0, vx, acc[0][0]); acc[0][1] = fma(p0, vy, acc[0][1]);
            acc[0][2] = fma(p0, vz, acc[0][2]); acc[0][3] = fma(p0, vw, acc[0][3]);
            acc[1][0] = fma(p1, vx, acc[1][0]); acc[1][1] = fma(p1, vy, acc[1][1]);
            acc[1][2] = fma(p1, vz, acc[1][2]); acc[1][3] = fma(p1, vw, acc[1][3]);
            acc[2][0] = fma(p2, vx, acc[2][0]); acc[2][1] = fma(p2, vy, acc[2][1]);
            acc[2][2] = fma(p2, vz, acc[2][2]); acc[2][3] = fma(p2, vw, acc[2][3]);
            acc[3][0] = fma(p3, vx, acc[3][0]); acc[3][1] = fma(p3, vy, acc[3][1]);
            acc[3][2] = fma(p3, vz, acc[3][2]); acc[3][3] = fma(p3, vw, acc[3][3]);
        }
        {
            double vx = (double)vfB.x, vy = (double)vfB.y;
            double vz = (double)vfB.z, vw = (double)vfB.w;
            double p0 = (double)pB[0], p1 = (double)pB[1];
            double p2 = (double)pB[2], p3 = (double)pB[3];
            acc[0][0] = fma(p0, vx, acc[0][0]); acc[0][1] = fma(p0, vy, acc[0][1]);
            acc[0][2] = fma(p0, vz, acc[0][2]); acc[0][3] = fma(p0, vw, acc[0][3]);
            acc[1][0] = fma(p1, vx, acc[1][0]); acc[1][1] = fma(p1, vy, acc[1][1]);
            acc[1][2] = fma(p1, vz, acc[1][2]); acc[1][3] = fma(p1, vw, acc[1][3]);
            acc[2][0] = fma(p2, vx, acc[2][0]); acc[2][1] = fma(p2, vy, acc[2][1]);
            acc[2][2] = fma(p2, vz, acc[2][2]); acc[2][3] = fma(p2, vw, acc[2][3]);
            acc[3][0] = fma(p3, vx, acc[3][0]); acc[3][1] = fma(p3, vy, acc[3][1]);
            acc[3][2] = fma(p3, vz, acc[3][2]); acc[3][3] = fma(p3, vw, acc[3][3]);
        }
    }

    // merge l across the 4 clusters (lanes within a cluster hold identical l)
    #pragma unroll
    for (int g = 0; g < NG; ++g) {
        l[g] += __shfl_xor(l[g], 16);
        l[g] += __shfl_xor(l[g], 32);
    }
    // merge acc across halves: disjoint key sets, SAME m (wave-uniform) -> plain add
    #pragma unroll
    for (int g = 0; g < NG; ++g) {
        #pragma unroll
        for (int j = 0; j < 4; ++j)
            acc[g][j] += __shfl_xor(acc[g][j], 32);
    }

    if (half == 0) {
        #pragma unroll
        for (int g = 0; g < NG; ++g) {
            #pragma unroll
            for (int j = 0; j < 4; ++j)
                s_acc[wave][g][l32 * 4 + j] = acc[g][j];
        }
        if (l32 == 0) {
            #pragma unroll
            for (int g = 0; g < NG; ++g) { s_m[wave][g] = m[g]; s_l[wave][g] = l[g]; }
        }
    }
    __syncthreads();

    // per-g global max + weights + denominator
    if (tid < NG) {
        int g = tid;
        float M = -INFINITY;
        for (int pa = 0; pa < WAVES; ++pa) M = fmaxf(M, s_m[pa][g]);
        double ltot = 0.0;
        for (int pa = 0; pa < WAVES; ++pa) {
            double w = exp((double)(s_m[pa][g] - M));
            s_w[pa][g] = w;
            ltot += s_l[pa][g] * w;
        }
        s_lt[g] = ltot;
    }
    __syncthreads();

    // 512 outputs, 512 threads: (g,d)
    {
        const float qs = qscale[0];
        int g = tid >> 7;
        int d = tid & 127;
        double o = 0.0;
        for (int pa = 0; pa < WAVES; ++pa)
            o += s_acc[pa][g][d] * s_w[pa][g];
        o /= s_lt[g];
        float x = (float)o;
        x = x / qs;
        out[((size_t)b * NHQ + (size_t)(h * NG + g)) * ND + d] = quant_e4m3(x);
    }
}

extern "C" void kernel_launch(void* const* d_in, const int* in_sizes, int n_in,
                              void* d_out, int out_size, void* d_ws, size_t ws_size,
                              hipStream_t stream) {
    (void)in_sizes; (void)n_in; (void)d_ws; (void)ws_size; (void)out_size;
    const float* q  = (const float*)d_in[0];
    const float* k  = (const float*)d_in[1];
    const float* v  = (const float*)d_in[2];
    const float* qs = (const float*)d_in[3];
    float* o = (float*)d_out;
    hipLaunchKernelGGL(attn_decode_quant, dim3(NB * NHKV), dim3(NTHREADS), 0, stream,
                       q, k, v, qs, o);
}

// Round 8
// 372.296 us; speedup vs baseline: 1.0765x; 1.0765x over previous
//
#include <hip/hip_runtime.h>
#include <math.h>

#define NB    64
#define NS    4096
#define NHQ   32
#define NHKV  8
#define ND    128
#define NG    4            // NHQ / NHKV
#define WAVES 8
#define NTHREADS (WAVES*64)
#define ROUNDS ((NS/WAVES)/4)   // 128 rounds of 4 keys per wave

// exact fp32 -> e4m3fn (RNE, clip +-448) returned as fp32
__device__ __forceinline__ float quant_e4m3(float x) {
    float a = fabsf(x);
    a = fminf(a, 448.0f);
    unsigned ui = __float_as_uint(a);
    int e  = (int)(ui >> 23) - 127;
    int se = (e < -6 ? -6 : e) - 3;          // step exponent (denormal step = 2^-9)
    float stp = __uint_as_float((unsigned)(se + 127) << 23);
    float qv  = rintf(a / stp) * stp;        // a/stp exact (stp is pow2), rintf = RNE
    return copysignf(qv, x);
}

// launch_bounds(512,2): 128-VGPR budget. (512,4) forced 64 VGPRs -> 0.8 GB of
// scratch spill per dispatch (r4/r5 counters: WRITE_SIZE ~836 MB vs 1 MB output).
// Identity block mapping: XCD-grouping swizzle measured -6.7% (r7) -- default
// round-robin spreads each batch's streams across all 8 L2s, which is better.
__global__ __launch_bounds__(NTHREADS, 2) void attn_decode_quant(
    const float* __restrict__ qin,
    const float* __restrict__ kc,
    const float* __restrict__ vc,
    const float* __restrict__ qscale,
    float* __restrict__ out)
{
    __shared__ double s_acc[WAVES][NG][ND];   // 32 KB
    __shared__ double s_l[WAVES][NG];
    __shared__ float  s_m[WAVES][NG];
    __shared__ double s_w[WAVES][NG];
    __shared__ double s_lt[NG];

    const int bh   = blockIdx.x;
    const int b    = bh >> 3;
    const int h    = bh & 7;
    const int tid  = threadIdx.x;
    const int wave = tid >> 6;
    const int lane = tid & 63;
    const int c    = lane >> 4;           // key-slot within round (0..3)
    const int e    = lane & 15;           // elem slot within cluster
    const int half = lane >> 5;
    const int l32  = lane & 31;

    const float sm_scale = (float)(1.0 / (double)sqrtf(128.0f));

    // q fragments, cluster layout: q[b, h*4+g, 4e + 64j .. +4)
    float4 qf[NG][2];
    {
        const float* qb = qin + ((size_t)b * NHQ + (size_t)h * NG) * ND;
        #pragma unroll
        for (int g = 0; g < NG; ++g) {
            #pragma unroll
            for (int j = 0; j < 2; ++j)
                qf[g][j] = *(const float4*)(qb + g * ND + 4 * e + 64 * j);
        }
    }

    const size_t rs = (size_t)NHKV * ND;  // 1024 floats = 4 KB between rows
    const float* kb = kc + ((size_t)b * NS * NHKV + h) * ND;
    const float* vb = vc + ((size_t)b * NS * NHKV + h) * ND;

    const int wbase = wave * (NS / WAVES);        // 512 keys per wave

    const float* kp = kb + (size_t)(wbase + c) * rs + 4 * e;       // rows 4r+c
    const float* vp = vb + (size_t)(wbase + half) * rs + 4 * l32;  // rows 4r+half, +2

    float  m[NG];
    double l[NG];
    double acc[NG][4];
    #pragma unroll
    for (int g = 0; g < NG; ++g) {
        m[g] = -INFINITY; l[g] = 0.0;
        #pragma unroll
        for (int j = 0; j < 4; ++j) acc[g][j] = 0.0;
    }

    // 1-round-deep register pipeline for BOTH K and V
    float4 kqA = *(const float4*)(kp);
    float4 kqB = *(const float4*)(kp + 64);
    float4 vqA = *(const float4*)(vp);
    float4 vqB = *(const float4*)(vp + 2 * rs);

    for (int r = 0; r < ROUNDS; ++r) {
        float4 kfA = kqA, kfB = kqB, vfA = vqA, vfB = vqB;
        int rn = (r + 1 < ROUNDS) ? (r + 1) : r;
        {
            const float* kn = kp + (size_t)(4 * rn) * rs;
            const float* vn = vp + (size_t)(4 * rn) * rs;
            kqA = *(const float4*)(kn);
            kqB = *(const float4*)(kn + 64);
            vqA = *(const float4*)(vn);
            vqB = *(const float4*)(vn + 2 * rs);
        }

        // ---- scores: 4 keys (one per cluster), 16-lane reduce ----
        float s[NG];
        #pragma unroll
        for (int g = 0; g < NG; ++g) {
            float sd = qf[g][0].x * kfA.x;
            sd = fmaf(qf[g][0].y, kfA.y, sd);
            sd = fmaf(qf[g][0].z, kfA.z, sd);
            sd = fmaf(qf[g][0].w, kfA.w, sd);
            sd = fmaf(qf[g][1].x, kfB.x, sd);
            sd = fmaf(qf[g][1].y, kfB.y, sd);
            sd = fmaf(qf[g][1].z, kfB.z, sd);
            sd = fmaf(qf[g][1].w, kfB.w, sd);
            s[g] = sd;
        }
        #pragma unroll
        for (int g = 0; g < NG; ++g) {
            #pragma unroll
            for (int mask = 1; mask < 16; mask <<= 1)
                s[g] += __shfl_xor(s[g], mask);
            s[g] *= sm_scale;
        }

        // wave-uniform round max per group; rare rescale branch (once per 4 keys)
        float rm[NG];
        #pragma unroll
        for (int g = 0; g < NG; ++g) {
            float t = s[g];
            t = fmaxf(t, __shfl_xor(t, 16));
            t = fmaxf(t, __shfl_xor(t, 32));
            rm[g] = t;
        }
        if (rm[0] > m[0] || rm[1] > m[1] || rm[2] > m[2] || rm[3] > m[3]) {
            #pragma unroll
            for (int g = 0; g < NG; ++g) {
                if (rm[g] > m[g]) {
                    double corr = exp((double)(m[g] - rm[g]));   // exp(-inf)=0 first time
                    l[g] *= corr;
                    acc[g][0] *= corr; acc[g][1] *= corr;
                    acc[g][2] *= corr; acc[g][3] *= corr;
                    m[g] = rm[g];
                }
            }
        }

        // p for this lane's key; l accumulates per-cluster (merged at end)
        float p[NG];
        #pragma unroll
        for (int g = 0; g < NG; ++g) {
            p[g] = expf(s[g] - m[g]);
            l[g] += (double)p[g];
        }

        // redistribute p to PV layout via intra-wave shuffles:
        // key A = 4r+half  -> cluster (half)   -> lane half*16
        // key B = 4r+2+half-> cluster (2+half) -> lane half*16+32
        const int srcA = half << 4;
        const int srcB = srcA + 32;
        float pA[NG], pB[NG];
        #pragma unroll
        for (int g = 0; g < NG; ++g) {
            pA[g] = __shfl(p[g], srcA);
            pB[g] = __shfl(p[g], srcB);
        }

        // ---- PV accumulate (fp64), round-1 layout ----
        {
            double vx = (double)vfA.x, vy = (double)vfA.y;
            double vz = (double)vfA.z, vw = (double)vfA.w;
            double p0 = (double)pA[0], p1 = (double)pA[1];
            double p2 = (double)pA[2], p3 = (double)pA[3];
            acc[0][0] = fma(p0, vx, acc[0][0]); acc[0][1] = fma(p0, vy, acc[0][1]);
            acc[0][2] = fma(p0, vz, acc[0][2]); acc[0][3] = fma(p0, vw, acc[0][3]);
            acc[1][0] = fma(p1, vx, acc[1][0]); acc[1][1] = fma(p1, vy, acc[1][1]);
            acc[1][2] = fma(p1, vz, acc[1][2]); acc[1][3] = fma(p1, vw, acc[1][3]);
            acc[2][0] = fma(p2, vx, acc[2][0]); acc[2][1] = fma(p2, vy, acc[2][1]);
            acc[2][2] = fma(p2, vz, acc[2][2]); acc[2][3] = fma(p2, vw, acc[2][3]);
            acc[3][0] = fma(p3, vx, acc[3][0]); acc[3][1] = fma(p3, vy, acc[3][1]);
            acc[3][2] = fma(p3, vz, acc[3][2]); acc[3][3] = fma(p3, vw, acc[3][3]);
        }
        {
            double vx = (double)vfB.x, vy = (double)vfB.y;
            double vz = (double)vfB.z, vw = (double)vfB.w;
            double p0 = (double)pB[0], p1 = (double)pB[1];
            double p2 = (double)pB[2], p3 = (double)pB[3];
            acc[0][0] = fma(p0, vx, acc[0][0]); acc[0][1] = fma(p0, vy, acc[0][1]);
            acc[0][2] = fma(p0, vz, acc[0][2]); acc[0][3] = fma(p0, vw, acc[0][3]);
            acc[1][0] = fma(p1, vx, acc[1][0]); acc[1][1] = fma(p1, vy, acc[1][1]);
            acc[1][2] = fma(p1, vz, acc[1][2]); acc[1][3] = fma(p1, vw, acc[1][3]);
            acc[2][0] = fma(p2, vx, acc[2][0]); acc[2][1] = fma(p2, vy, acc[2][1]);
            acc[2][2] = fma(p2, vz, acc[2][2]); acc[2][3] = fma(p2, vw, acc[2][3]);
            acc[3][0] = fma(p3, vx, acc[3][0]); acc[3][1] = fma(p3, vy, acc[3][1]);
            acc[3][2] = fma(p3, vz, acc[3][2]); acc[3][3] = fma(p3, vw, acc[3][3]);
        }
    }

    // merge l across the 4 clusters (lanes within a cluster hold identical l)
    #pragma unroll
    for (int g = 0; g < NG; ++g) {
        l[g] += __shfl_xor(l[g], 16);
        l[g] += __shfl_xor(l[g], 32);
    }
    // merge acc across halves: disjoint key sets, SAME m (wave-uniform) -> plain add
    #pragma unroll
    for (int g = 0; g < NG; ++g) {
        #pragma unroll
        for (int j = 0; j < 4; ++j)
            acc[g][j] += __shfl_xor(acc[g][j], 32);
    }

    if (half == 0) {
        #pragma unroll
        for (int g = 0; g < NG; ++g) {
            #pragma unroll
            for (int j = 0; j < 4; ++j)
                s_acc[wave][g][l32 * 4 + j] = acc[g][j];
        }
        if (l32 == 0) {
            #pragma unroll
            for (int g = 0; g < NG; ++g) { s_m[wave][g] = m[g]; s_l[wave][g] = l[g]; }
        }
    }
    __syncthreads();

    // per-g global max + weights + denominator
    if (tid < NG) {
        int g = tid;
        float M = -INFINITY;
        for (int pa = 0; pa < WAVES; ++pa) M = fmaxf(M, s_m[pa][g]);
        double ltot = 0.0;
        for (int pa = 0; pa < WAVES; ++pa) {
            double w = exp((double)(s_m[pa][g] - M));
            s_w[pa][g] = w;
            ltot += s_l[pa][g] * w;
        }
        s_lt[g] = ltot;
    }
    __syncthreads();

    // 512 outputs, 512 threads: (g,d)
    {
        const float qs = qscale[0];
        int g = tid >> 7;
        int d = tid & 127;
        double o = 0.0;
        for (int pa = 0; pa < WAVES; ++pa)
            o += s_acc[pa][g][d] * s_w[pa][g];
        o /= s_lt[g];
        float x = (float)o;
        x = x / qs;
        out[((size_t)b * NHQ + (size_t)(h * NG + g)) * ND + d] = quant_e4m3(x);
    }
}

extern "C" void kernel_launch(void* const* d_in, const int* in_sizes, int n_in,
                              void* d_out, int out_size, void* d_ws, size_t ws_size,
                              hipStream_t stream) {
    (void)in_sizes; (void)n_in; (void)d_ws; (void)ws_size; (void)out_size;
    const float* q  = (const float*)d_in[0];
    const float* k  = (const float*)d_in[1];
    const float* v  = (const float*)d_in[2];
    const float* qs = (const float*)d_in[3];
    float* o = (float*)d_out;
    hipLaunchKernelGGL(attn_decode_quant, dim3(NB * NHKV), dim3(NTHREADS), 0, stream,
                       q, k, v, qs, o);
}